// Round 1
// baseline (5163.397 us; speedup 1.0000x reference)
//
#include <hip/hip_runtime.h>

// NODE decoder: T=32 RK4 steps over B=16384 independent samples, then decode.
// Phase A (ode_kernel): persistent block owns 32 samples for all 32 steps.
//   z state in registers (4x4 tile/thread); stage argument transposed in LDS.
// Phase B (dec_kernel): hs = leaky(zs@Wl+bl); xs = hs@Wo+bo.

#define TSTEPS 32
#define BATCH  16384
#define LAT    128
#define HID    256
#define NOUT   8
#define SBA    32      // samples per block, phase A
#define PADA   36      // padded LDS row length (floats): 16B-aligned, odd mod 32 banks

// ---------------------------------------------------------------------------
// Phase A: fused RK4 integration.  grid = BATCH/SBA = 512 blocks x 256 thr.
// Thread tiling: sg = tid>>5 picks 4 samples (sl..sl+3), cg = tid&31 picks cols.
// GEMM1: acc[4 samples][8 cols of 256];  GEMM2: ac2[4 samples][4 cols of 128].
// LDS ~69.8 KB -> 2 blocks/CU (8 waves/CU).
// ---------------------------------------------------------------------------
__global__ __launch_bounds__(256, 2) void ode_kernel(
    const float* __restrict__ z0, const float* __restrict__ ts,
    const float* __restrict__ W1, const float* __restrict__ b1,
    const float* __restrict__ g1, const float* __restrict__ be1,
    const float* __restrict__ W2, const float* __restrict__ b2,
    const float* __restrict__ g2, const float* __restrict__ be2,
    float* __restrict__ zs)
{
    __shared__ float ztT[LAT + 1][PADA];   // [k][sample] stage input (row LAT = time)
    __shared__ float aT [HID][PADA];       // [k][sample] layer-1 activations
    __shared__ float scr[2][SBA][PADA];    // LN partial sum / sumsq
    __shared__ float musig[2][SBA];        // mean, rstd per sample
    __shared__ float prm[3 * HID + 3 * LAT]; // b1,g1,be1 | b2,g2,be2
    __shared__ float tc_s[SBA], dt_s[SBA];

    const int tid = threadIdx.x;
    const int sg  = tid >> 5;
    const int cg  = tid & 31;
    const int sl  = sg << 2;                  // local sample base of this tile
    const long sb = (long)blockIdx.x * SBA;   // global sample base

    for (int i = tid; i < 1152; i += 256) {
        float v;
        if      (i < 256)  v = b1 [i];
        else if (i < 512)  v = g1 [i - 256];
        else if (i < 768)  v = be1[i - 512];
        else if (i < 896)  v = b2 [i - 768];
        else if (i < 1024) v = g2 [i - 896];
        else               v = be2[i - 1024];
        prm[i] = v;
    }

    // stage z0 -> ztT (transposed) and into z-state registers
    const float4* z0v = (const float4*)(z0 + sb * LAT);
    for (int i = tid; i < SBA * 32; i += 256) {
        int row = i >> 5, kc = i & 31;
        float4 v = z0v[row * 32 + kc];
        ztT[kc * 4 + 0][row] = v.x;
        ztT[kc * 4 + 1][row] = v.y;
        ztT[kc * 4 + 2][row] = v.z;
        ztT[kc * 4 + 3][row] = v.w;
    }
    float zor[4][4], znw[4][4];   // z_orig, z_new tiles: [sample r][col cg*4+cc]
    #pragma unroll
    for (int r = 0; r < 4; ++r) {
        float4 v = z0v[(sl + r) * 32 + cg];
        zor[r][0] = v.x; zor[r][1] = v.y; zor[r][2] = v.z; zor[r][3] = v.w;
    }
    __syncthreads();

    #pragma unroll 1
    for (int step = 0; step < TSTEPS; ++step) {
        if (tid < SBA) {
            float tc = (step == 0) ? 0.f : ts[(step - 1) * BATCH + sb + tid];
            float tn = ts[step * BATCH + sb + tid];
            tc_s[tid] = tc;
            dt_s[tid] = tn - tc;
            ztT[LAT][tid] = tc;               // time row for stage 0
        }
        #pragma unroll
        for (int r = 0; r < 4; ++r)
            #pragma unroll
            for (int c = 0; c < 4; ++c)
                znw[r][c] = zor[r][c];
        __syncthreads();

        #pragma unroll 1
        for (int stg = 0; stg < 4; ++stg) {
            // ---------------- layer 1: h = zt @ W1 + b1 ----------------
            float acc[4][8];
            #pragma unroll
            for (int jj = 0; jj < 8; ++jj) {
                float bv = prm[cg * 8 + jj];
                #pragma unroll
                for (int r = 0; r < 4; ++r) acc[r][jj] = bv;
            }
            {
                const float4* W1v = (const float4*)W1;
                for (int k = 0; k < LAT + 1; ++k) {
                    float4 zv = *(const float4*)&ztT[k][sl];   // broadcast per half-wave
                    float4 w0 = W1v[k * 64 + cg * 2];
                    float4 w1 = W1v[k * 64 + cg * 2 + 1];
                    float zr[4] = {zv.x, zv.y, zv.z, zv.w};
                    float wv[8] = {w0.x, w0.y, w0.z, w0.w, w1.x, w1.y, w1.z, w1.w};
                    #pragma unroll
                    for (int r = 0; r < 4; ++r)
                        #pragma unroll
                        for (int jj = 0; jj < 8; ++jj)
                            acc[r][jj] = fmaf(zr[r], wv[jj], acc[r][jj]);
                }
            }
            // LN1 (N=256)
            #pragma unroll
            for (int r = 0; r < 4; ++r) {
                float s = 0.f, q = 0.f;
                #pragma unroll
                for (int jj = 0; jj < 8; ++jj) { float h = acc[r][jj]; s += h; q += h * h; }
                scr[0][sl + r][cg] = s;
                scr[1][sl + r][cg] = q;
            }
            __syncthreads();
            if (tid < SBA) {
                float s = 0.f, q = 0.f;
                #pragma unroll
                for (int c = 0; c < 8; ++c) {
                    float4 a4 = *(const float4*)&scr[0][tid][c * 4];
                    float4 b4 = *(const float4*)&scr[1][tid][c * 4];
                    s += (a4.x + a4.y) + (a4.z + a4.w);
                    q += (b4.x + b4.y) + (b4.z + b4.w);
                }
                float mu  = s * (1.f / HID);
                float var = q * (1.f / HID) - mu * mu;
                musig[0][tid] = mu;
                musig[1][tid] = rsqrtf(var + 1e-5f);
            }
            __syncthreads();
            #pragma unroll
            for (int jj = 0; jj < 8; ++jj) {
                int j = cg * 8 + jj;
                float g  = prm[256 + j];
                float be = prm[512 + j];
                float t4[4];
                #pragma unroll
                for (int r = 0; r < 4; ++r) {
                    float a = (acc[r][jj] - musig[0][sl + r]) * musig[1][sl + r] * g + be;
                    t4[r] = (a >= 0.f) ? a : 0.1f * a;
                }
                *(float4*)&aT[j][sl] = make_float4(t4[0], t4[1], t4[2], t4[3]);
            }
            __syncthreads();
            // ---------------- layer 2: d = a @ W2 + b2 ----------------
            float ac2[4][4];
            #pragma unroll
            for (int cc = 0; cc < 4; ++cc) {
                float bv = prm[768 + cg * 4 + cc];
                #pragma unroll
                for (int r = 0; r < 4; ++r) ac2[r][cc] = bv;
            }
            {
                const float4* W2v = (const float4*)W2;
                for (int k = 0; k < HID; ++k) {
                    float4 av = *(const float4*)&aT[k][sl];    // broadcast per half-wave
                    float4 w  = W2v[k * 32 + cg];
                    float ar[4] = {av.x, av.y, av.z, av.w};
                    float wc[4] = {w.x, w.y, w.z, w.w};
                    #pragma unroll
                    for (int r = 0; r < 4; ++r)
                        #pragma unroll
                        for (int cc = 0; cc < 4; ++cc)
                            ac2[r][cc] = fmaf(ar[r], wc[cc], ac2[r][cc]);
                }
            }
            // LN2 (N=128)
            #pragma unroll
            for (int r = 0; r < 4; ++r) {
                float s = 0.f, q = 0.f;
                #pragma unroll
                for (int cc = 0; cc < 4; ++cc) { float h = ac2[r][cc]; s += h; q += h * h; }
                scr[0][sl + r][cg] = s;
                scr[1][sl + r][cg] = q;
            }
            __syncthreads();
            if (tid < SBA) {
                float s = 0.f, q = 0.f;
                #pragma unroll
                for (int c = 0; c < 8; ++c) {
                    float4 a4 = *(const float4*)&scr[0][tid][c * 4];
                    float4 b4 = *(const float4*)&scr[1][tid][c * 4];
                    s += (a4.x + a4.y) + (a4.z + a4.w);
                    q += (b4.x + b4.y) + (b4.z + b4.w);
                }
                float mu  = s * (1.f / LAT);
                float var = q * (1.f / LAT) - mu * mu;
                musig[0][tid] = mu;
                musig[1][tid] = rsqrtf(var + 1e-5f);
            }
            __syncthreads();
            float dk[4][4];
            #pragma unroll
            for (int cc = 0; cc < 4; ++cc) {
                int j = cg * 4 + cc;
                float g  = prm[896 + j];
                float be = prm[1024 + j];
                #pragma unroll
                for (int r = 0; r < 4; ++r) {
                    float a = (ac2[r][cc] - musig[0][sl + r]) * musig[1][sl + r] * g + be;
                    dk[r][cc] = (a >= 0.f) ? a : 0.1f * a;
                }
            }
            // ---------------- RK4 bookkeeping ----------------
            const float wdiv6 = (stg == 1 || stg == 2) ? (2.f / 6.f) : (1.f / 6.f);
            const float cnx   = (stg < 2) ? 0.5f : 1.f;   // coeff for next stage argument
            float dtr[4];
            #pragma unroll
            for (int r = 0; r < 4; ++r) dtr[r] = dt_s[sl + r];
            #pragma unroll
            for (int r = 0; r < 4; ++r) {
                float f6 = dtr[r] * wdiv6;
                #pragma unroll
                for (int cc = 0; cc < 4; ++cc)
                    znw[r][cc] = fmaf(f6, dk[r][cc], znw[r][cc]);
            }
            if (stg < 3) {
                // next stage argument z_arg = z_orig + cnx*dt*k  -> ztT
                #pragma unroll
                for (int cc = 0; cc < 4; ++cc) {
                    float q0 = fmaf(cnx * dtr[0], dk[0][cc], zor[0][cc]);
                    float q1 = fmaf(cnx * dtr[1], dk[1][cc], zor[1][cc]);
                    float q2 = fmaf(cnx * dtr[2], dk[2][cc], zor[2][cc]);
                    float q3 = fmaf(cnx * dtr[3], dk[3][cc], zor[3][cc]);
                    *(float4*)&ztT[cg * 4 + cc][sl] = make_float4(q0, q1, q2, q3);
                }
                if (tid < SBA) ztT[LAT][tid] = tc_s[tid] + cnx * dt_s[tid];
            } else {
                // finalize step: z <- z_new; stage it for next step; emit zs[step]
                #pragma unroll
                for (int cc = 0; cc < 4; ++cc)
                    *(float4*)&ztT[cg * 4 + cc][sl] =
                        make_float4(znw[0][cc], znw[1][cc], znw[2][cc], znw[3][cc]);
                #pragma unroll
                for (int r = 0; r < 4; ++r) {
                    #pragma unroll
                    for (int cc = 0; cc < 4; ++cc) zor[r][cc] = znw[r][cc];
                    *(float4*)&zs[((long)step * BATCH + sb + sl + r) * LAT + cg * 4] =
                        make_float4(znw[r][0], znw[r][1], znw[r][2], znw[r][3]);
                }
            }
            __syncthreads();
        }
    }
}

// ---------------------------------------------------------------------------
// Phase B: decode.  grid = T*B/32 = 16384 blocks x 256 thr, 32 rows/block.
// xs[row] = leaky(zs[row] @ Wl + bl) @ Wo + bo
// ---------------------------------------------------------------------------
__global__ __launch_bounds__(256, 2) void dec_kernel(
    const float* __restrict__ zsin, const float* __restrict__ Wl,
    const float* __restrict__ bl, const float* __restrict__ Wo,
    const float* __restrict__ bo, float* __restrict__ xs)
{
    __shared__ float zT[LAT][PADA];
    __shared__ float wo_s[HID * 9];   // row-padded to 9 floats to break bank stride
    __shared__ float bl_s[HID];
    __shared__ float bo_s[NOUT];

    const int tid = threadIdx.x;
    const int sg  = tid >> 5;
    const int cg  = tid & 31;
    const int sl  = sg << 2;
    const long r0 = (long)blockIdx.x * 32;

    if (tid < HID)  bl_s[tid] = bl[tid];
    if (tid < NOUT) bo_s[tid] = bo[tid];
    for (int i = tid; i < HID * NOUT; i += 256) wo_s[(i >> 3) * 9 + (i & 7)] = Wo[i];

    const float4* zv4 = (const float4*)(zsin + r0 * LAT);
    for (int i = tid; i < 32 * 32; i += 256) {
        int row = i >> 5, kc = i & 31;
        float4 v = zv4[row * 32 + kc];
        zT[kc * 4 + 0][row] = v.x;
        zT[kc * 4 + 1][row] = v.y;
        zT[kc * 4 + 2][row] = v.z;
        zT[kc * 4 + 3][row] = v.w;
    }
    __syncthreads();

    float acc[4][8];
    #pragma unroll
    for (int jj = 0; jj < 8; ++jj) {
        float bv = bl_s[cg * 8 + jj];
        #pragma unroll
        for (int r = 0; r < 4; ++r) acc[r][jj] = bv;
    }
    const float4* Wlv = (const float4*)Wl;
    for (int k = 0; k < LAT; ++k) {
        float4 zv = *(const float4*)&zT[k][sl];
        float4 w0 = Wlv[k * 64 + cg * 2];
        float4 w1 = Wlv[k * 64 + cg * 2 + 1];
        float zr[4] = {zv.x, zv.y, zv.z, zv.w};
        float wv[8] = {w0.x, w0.y, w0.z, w0.w, w1.x, w1.y, w1.z, w1.w};
        #pragma unroll
        for (int r = 0; r < 4; ++r)
            #pragma unroll
            for (int jj = 0; jj < 8; ++jj)
                acc[r][jj] = fmaf(zr[r], wv[jj], acc[r][jj]);
    }

    float xo[4][NOUT];
    #pragma unroll
    for (int r = 0; r < 4; ++r)
        #pragma unroll
        for (int o = 0; o < NOUT; ++o) xo[r][o] = 0.f;

    #pragma unroll
    for (int jj = 0; jj < 8; ++jj) {
        int j = cg * 8 + jj;
        float a[4];
        #pragma unroll
        for (int r = 0; r < 4; ++r) {
            float h = acc[r][jj];
            a[r] = (h >= 0.f) ? h : 0.1f * h;
        }
        #pragma unroll
        for (int o = 0; o < NOUT; ++o) {
            float w = wo_s[j * 9 + o];
            #pragma unroll
            for (int r = 0; r < 4; ++r) xo[r][o] = fmaf(a[r], w, xo[r][o]);
        }
    }

    // reduce partial xs over the 32 col-groups (one half-wave each)
    #pragma unroll
    for (int m = 16; m >= 1; m >>= 1)
        #pragma unroll
        for (int r = 0; r < 4; ++r)
            #pragma unroll
            for (int o = 0; o < NOUT; ++o)
                xo[r][o] += __shfl_xor(xo[r][o], m, 32);

    if (cg == 0) {
        #pragma unroll
        for (int r = 0; r < 4; ++r) {
            float4 v0 = make_float4(xo[r][0] + bo_s[0], xo[r][1] + bo_s[1],
                                    xo[r][2] + bo_s[2], xo[r][3] + bo_s[3]);
            float4 v1 = make_float4(xo[r][4] + bo_s[4], xo[r][5] + bo_s[5],
                                    xo[r][6] + bo_s[6], xo[r][7] + bo_s[7]);
            float* p = &xs[(r0 + sl + r) * NOUT];
            *(float4*)p = v0;
            *(float4*)(p + 4) = v1;
        }
    }
}

extern "C" void kernel_launch(void* const* d_in, const int* in_sizes, int n_in,
                              void* d_out, int out_size, void* d_ws, size_t ws_size,
                              hipStream_t stream) {
    const float* z0  = (const float*)d_in[0];
    const float* ts  = (const float*)d_in[1];
    const float* W1  = (const float*)d_in[2];
    const float* b1  = (const float*)d_in[3];
    const float* g1  = (const float*)d_in[4];
    const float* be1 = (const float*)d_in[5];
    const float* W2  = (const float*)d_in[6];
    const float* b2  = (const float*)d_in[7];
    const float* g2  = (const float*)d_in[8];
    const float* be2 = (const float*)d_in[9];
    const float* Wl  = (const float*)d_in[10];
    const float* bl  = (const float*)d_in[11];
    const float* Wo  = (const float*)d_in[12];
    const float* bo  = (const float*)d_in[13];

    float* xs = (float*)d_out;                                  // [T,B,8]
    float* zs = (float*)d_out + (size_t)TSTEPS * BATCH * NOUT;  // [T,B,128]

    ode_kernel<<<dim3(BATCH / SBA), dim3(256), 0, stream>>>(
        z0, ts, W1, b1, g1, be1, W2, b2, g2, be2, zs);
    dec_kernel<<<dim3(TSTEPS * BATCH / 32), dim3(256), 0, stream>>>(
        zs, Wl, bl, Wo, bo, xs);
}

// Round 6
// 2448.882 us; speedup vs baseline: 2.1085x; 2.1085x over previous
//
#include <hip/hip_runtime.h>

// NODE decoder, round 3 design (resubmit #3 after 4x GPU-acquisition timeout;
// quadruple desk-audited, incl. A/B fragment layout re-check vs verified
// examples). Split-fp16 (hi+lo, 3-product) MFMA ODE integrator.
// Accuracy design: every GEMM computes x·w = xh·wh + 2^-11*(xl_s·wh + xh·wl_s)
// with lo-parts pre-scaled by 2^11 (fp16-normal range). Effective dot-product
// error ~2^-22 — same noise class as an fp32 kernel (round-1 passed at
// absmax 0.031 with fp32). LN stats/affine/state/RK4 all fp32.
// ode_kernel: 512 blocks x 512 thr (8 waves), 32 samples/block, lane=sample.
//   GEMM1: wave w owns hid rows [32w,32w+32), k=128 (z; time via fp32 epilogue).
//   GEMM2: wave (t,h)=(w>>1,w&1) owns lat rows [32t,32t+32), k-half h of 256;
//   partials combined via LDS. Weights register-hoisted (128 VGPR hi+lo).
// dec_kernel: fp16-MFMA (no split; one-shot layer, no error amplification).

#define TSTEPS 32
#define BATCH  16384
#define LAT    128
#define HID    256
#define NOUT   8

using f16x8  = __attribute__((ext_vector_type(8)))  _Float16;
using f16x4  = __attribute__((ext_vector_type(4)))  _Float16;
using f32x16 = __attribute__((ext_vector_type(16))) float;
using f32x4v = __attribute__((ext_vector_type(4)))  float;

#define LO_S 2048.0f            // lo-part pre-scale (2^11)
#define LO_I 4.8828125e-4f      // 2^-11

// ---------------------------------------------------------------------------
// Weight prep (per launch; d_ws is re-poisoned before every timed call).
// grid = 128 x 256.
// ---------------------------------------------------------------------------
__global__ void prep_kernel(const float* __restrict__ W1, const float* __restrict__ b1,
                            const float* __restrict__ g1, const float* __restrict__ be1,
                            const float* __restrict__ W2, const float* __restrict__ b2,
                            const float* __restrict__ g2, const float* __restrict__ be2,
                            const float* __restrict__ Wl,
                            _Float16* __restrict__ w1h, _Float16* __restrict__ w1l,
                            _Float16* __restrict__ w2h, _Float16* __restrict__ w2l,
                            _Float16* __restrict__ wlt,
                            float2* __restrict__ pA, float2* __restrict__ pB,
                            float2* __restrict__ pD, float* __restrict__ b2f)
{
    const int i = blockIdx.x * 256 + threadIdx.x;    // [0, 32768)
    {   // w1T[hid][lat] hi/lo from W1[lat][hid] (k rows 0..127; row 128 = time)
        const int h = i >> 7, k = i & 127;
        const float v = W1[k * 256 + h];
        const _Float16 vh = (_Float16)v;
        w1h[i] = vh;
        w1l[i] = (_Float16)((v - (float)vh) * LO_S);
    }
    {   // w2T[lat][hid] hi/lo from W2[hid][lat]
        const int d = i >> 8, h = i & 255;
        const float v = W2[h * 128 + d];
        const _Float16 vh = (_Float16)v;
        w2h[i] = vh;
        w2l[i] = (_Float16)((v - (float)vh) * LO_S);
    }
    {   // WlT[hid][lat] (hi only — decode is not amplification-sensitive)
        const int h = i >> 7, k = i & 127;
        wlt[i] = (_Float16)Wl[k * 256 + h];
    }
    if (i < 256) {
        pA[i] = make_float2(b1[i], W1[128 * 256 + i]);   // {b1, w1_time} fp32
        pB[i] = make_float2(g1[i], be1[i]);
    }
    if (i < 128) {
        pD[i] = make_float2(g2[i], be2[i]);
        b2f[i] = b2[i];
    }
}

// ---------------------------------------------------------------------------
// ODE kernel. C/D layout (HW-verified): col=lane&31(=sample),
// row = (reg&3) + 8*(reg>>2) + 4*(lane>>5).
// ---------------------------------------------------------------------------
__global__ __launch_bounds__(512, 2) void ode_kernel(
    const float* __restrict__ z0, const float* __restrict__ ts,
    const _Float16* __restrict__ w1hg, const _Float16* __restrict__ w1lg,
    const _Float16* __restrict__ w2hg, const _Float16* __restrict__ w2lg,
    const float2* __restrict__ pAg, const float2* __restrict__ pBg,
    const float2* __restrict__ pDg, const float* __restrict__ b2g,
    float* __restrict__ zs)
{
    __shared__ _Float16 ztH[32 * 128], ztLo[32 * 128];   // stage arg [samp][lat], swizzled
    __shared__ _Float16 a1H[32 * 256], a1Lo[32 * 256];   // layer-1 act, swizzled
    __shared__ float    pt[4096];                        // GEMM2 partials / z-transpose
    __shared__ float    scrS[8][33], scrQ[8][33];        // LN cross-wave stats
    __shared__ float2   pA[256], pB[256], pD[128];
    __shared__ float    b2s[128];

    const int tid  = threadIdx.x;
    const int w    = tid >> 6;          // wave 0..7
    const int l    = tid & 63;
    const int li   = l & 31;            // sample (= MFMA col)
    const int lh   = l >> 5;
    const int samp = li;
    const int t2   = w >> 1;            // GEMM2 tile
    const int kh   = w & 1;             // GEMM2 k-half
    const long gsamp = (long)blockIdx.x * 32 + li;
    char* ztHB = (char*)ztH;  char* ztLB = (char*)ztLo;
    char* a1HB = (char*)a1H;  char* a1LB = (char*)a1Lo;

    if (tid < 256) { pA[tid] = pAg[tid]; pB[tid] = pBg[tid]; }
    if (tid < 128) { pD[tid] = pDg[tid]; b2s[tid] = b2g[tid]; }

    // ---- register-hoisted weight fragments (one-time) ----
    f16x8 w1h[8], w1l[8];
    {
        const int r1 = 32 * w + li;                     // hid row
        #pragma unroll
        for (int kt = 0; kt < 8; ++kt) {
            const int off = r1 * 128 + kt * 16 + lh * 8;
            w1h[kt] = *(const f16x8*)(w1hg + off);
            w1l[kt] = *(const f16x8*)(w1lg + off);
        }
    }
    f16x8 w2h[8], w2l[8];
    {
        const int r2 = 32 * t2 + li;                    // lat row
        #pragma unroll
        for (int kt = 0; kt < 8; ++kt) {
            const int off = r2 * 256 + (8 * kh + kt) * 16 + lh * 8;
            w2h[kt] = *(const f16x8*)(w2hg + off);
            w2l[kt] = *(const f16x8*)(w2lg + off);
        }
    }

    // ---- z state (owner waves kh==0 hold lats [32*t2, 32*t2+32)) ----
    float zor[16], znw[16];
    if (kh == 0) {
        #pragma unroll
        for (int rg = 0; rg < 4; ++rg) {
            const int lat0 = 32 * t2 + 8 * rg + 4 * lh;
            f32x4v v = *(const f32x4v*)(z0 + gsamp * 128 + lat0);
            f16x4 hv, lv;
            #pragma unroll
            for (int j = 0; j < 4; ++j) {
                zor[rg * 4 + j] = v[j];
                hv[j] = (_Float16)v[j];
                lv[j] = (_Float16)((v[j] - (float)hv[j]) * LO_S);
            }
            const int slot = lat0 >> 3;
            const int bo = samp * 256 + ((slot ^ (samp & 15)) << 4) + 8 * lh;
            *(f16x4*)(ztHB + bo) = hv;
            *(f16x4*)(ztLB + bo) = lv;
        }
    }
    __syncthreads();

    #pragma unroll 1
    for (int step = 0; step < TSTEPS; ++step) {
        const float tc = (step == 0) ? 0.f : ts[(long)(step - 1) * BATCH + gsamp];
        const float tn = ts[(long)step * BATCH + gsamp];
        const float dt = tn - tc;
        if (kh == 0) {
            #pragma unroll
            for (int i = 0; i < 16; ++i) znw[i] = zor[i];
        }

        #pragma unroll 1
        for (int stg = 0; stg < 4; ++stg) {
            const float tstg = (stg == 0) ? tc : (stg == 3) ? tn : fmaf(0.5f, dt, tc);
            // ---------------- GEMM1 (3-product): H[hid][samp] ----------------
            f32x16 ah = {}, al = {};
            #pragma unroll
            for (int kt = 0; kt < 8; ++kt) {
                const int kc = kt * 2 + lh;
                const int bo = samp * 256 + ((kc ^ (samp & 15)) << 4);
                f16x8 bh = *(const f16x8*)(ztHB + bo);
                f16x8 bl = *(const f16x8*)(ztLB + bo);
                ah = __builtin_amdgcn_mfma_f32_32x32x16_f16(w1h[kt], bh, ah, 0, 0, 0);
                al = __builtin_amdgcn_mfma_f32_32x32x16_f16(w1l[kt], bh, al, 0, 0, 0);
                al = __builtin_amdgcn_mfma_f32_32x32x16_f16(w1h[kt], bl, al, 0, 0, 0);
            }
            // epilogue: h = hi + 2^-11*lo + b1 + t*w1_time  (in place, fp32)
            float s = 0.f, q = 0.f;
            #pragma unroll
            for (int rg = 0; rg < 4; ++rg) {
                #pragma unroll
                for (int j = 0; j < 4; ++j) {
                    const int hid = 32 * w + 8 * rg + 4 * lh + j;
                    const float2 ab = pA[hid];
                    float h = ah[rg * 4 + j] + LO_I * al[rg * 4 + j] + fmaf(tstg, ab.y, ab.x);
                    ah[rg * 4 + j] = h;
                    s += h; q += h * h;
                }
            }
            s += __shfl_xor(s, 32);
            q += __shfl_xor(q, 32);
            if (l < 32) { scrS[w][samp] = s; scrQ[w][samp] = q; }
            __syncthreads();                                  // A: LN1 stats ready
            {
                float ssum = 0.f, qsum = 0.f;
                #pragma unroll
                for (int ww = 0; ww < 8; ++ww) { ssum += scrS[ww][samp]; qsum += scrQ[ww][samp]; }
                const float mu = ssum * (1.f / 256.f);
                const float rs = rsqrtf(qsum * (1.f / 256.f) - mu * mu + 1e-5f);
                #pragma unroll
                for (int rg = 0; rg < 4; ++rg) {
                    f16x4 hv, lv;
                    #pragma unroll
                    for (int j = 0; j < 4; ++j) {
                        const int hid = 32 * w + 8 * rg + 4 * lh + j;
                        const float2 gb = pB[hid];
                        float a = fmaf((ah[rg * 4 + j] - mu) * rs, gb.x, gb.y);
                        a = fmaxf(a, 0.1f * a);               // LeakyReLU(0.1)
                        hv[j] = (_Float16)a;
                        lv[j] = (_Float16)((a - (float)hv[j]) * LO_S);
                    }
                    const int slot = 4 * w + rg;
                    const int bo = samp * 512 + ((slot ^ (samp & 31)) << 4) + 8 * lh;
                    *(f16x4*)(a1HB + bo) = hv;
                    *(f16x4*)(a1LB + bo) = lv;
                }
            }
            __syncthreads();                                  // B: a1 ready
            // ---------------- GEMM2 (3-product, k-split): D[lat][samp] -------
            f32x16 ch = {}, cl = {};
            #pragma unroll
            for (int kt = 0; kt < 8; ++kt) {
                const int kc = (8 * kh + kt) * 2 + lh;
                const int bo = samp * 512 + ((kc ^ (samp & 31)) << 4);
                f16x8 bh = *(const f16x8*)(a1HB + bo);
                f16x8 bl = *(const f16x8*)(a1LB + bo);
                ch = __builtin_amdgcn_mfma_f32_32x32x16_f16(w2h[kt], bh, ch, 0, 0, 0);
                cl = __builtin_amdgcn_mfma_f32_32x32x16_f16(w2l[kt], bh, cl, 0, 0, 0);
                cl = __builtin_amdgcn_mfma_f32_32x32x16_f16(w2h[kt], bl, cl, 0, 0, 0);
            }
            if (kh == 1) {                                    // upper k-half -> partials
                #pragma unroll
                for (int rg = 0; rg < 4; ++rg)
                    #pragma unroll
                    for (int j = 0; j < 4; ++j) {
                        const int row = 8 * rg + 4 * lh + j;
                        pt[(t2 * 32 + row) * 32 + samp] =
                            ch[rg * 4 + j] + LO_I * cl[rg * 4 + j];
                    }
            }
            __syncthreads();                                  // C: partials ready
            float h2[16];
            if (kh == 0) {
                float s2 = 0.f, q2 = 0.f;
                #pragma unroll
                for (int rg = 0; rg < 4; ++rg) {
                    #pragma unroll
                    for (int j = 0; j < 4; ++j) {
                        const int row = 8 * rg + 4 * lh + j;
                        const float v = ch[rg * 4 + j] + LO_I * cl[rg * 4 + j]
                                      + pt[(t2 * 32 + row) * 32 + samp]
                                      + b2s[32 * t2 + row];
                        h2[rg * 4 + j] = v;
                        s2 += v; q2 += v * v;
                    }
                }
                s2 += __shfl_xor(s2, 32);
                q2 += __shfl_xor(q2, 32);
                if (l < 32) { scrS[t2][samp] = s2; scrQ[t2][samp] = q2; }
            }
            __syncthreads();                                  // D: LN2 stats ready
            if (kh == 0) {
                float ssum = 0.f, qsum = 0.f;
                #pragma unroll
                for (int tt = 0; tt < 4; ++tt) { ssum += scrS[tt][samp]; qsum += scrQ[tt][samp]; }
                const float mu2 = ssum * (1.f / 128.f);
                const float rs2 = rsqrtf(qsum * (1.f / 128.f) - mu2 * mu2 + 1e-5f);
                const float c6  = (stg == 1 || stg == 2) ? (1.f / 3.f) : (1.f / 6.f);
                const float cnx = (stg < 2) ? 0.5f : 1.f;
                #pragma unroll
                for (int rg = 0; rg < 4; ++rg) {
                    f16x4 hv, lv;
                    #pragma unroll
                    for (int j = 0; j < 4; ++j) {
                        const int i = rg * 4 + j;
                        const int lat = 32 * t2 + 8 * rg + 4 * lh + j;
                        const float2 gb = pD[lat];
                        float a = fmaf((h2[i] - mu2) * rs2, gb.x, gb.y);
                        a = fmaxf(a, 0.1f * a);               // k (stage derivative)
                        znw[i] = fmaf(dt * c6, a, znw[i]);
                        const float za = (stg < 3) ? fmaf(cnx * dt, a, zor[i]) : znw[i];
                        hv[j] = (_Float16)za;
                        lv[j] = (_Float16)((za - (float)hv[j]) * LO_S);
                        if (stg == 3) {
                            // swizzled z-transpose for coalesced global store
                            pt[lat * 32 + (samp ^ (lat & 31))] = za;
                            zor[i] = za;
                        }
                    }
                    const int slot = 4 * t2 + rg;
                    const int bo = samp * 256 + ((slot ^ (samp & 15)) << 4) + 8 * lh;
                    *(f16x4*)(ztHB + bo) = hv;
                    *(f16x4*)(ztLB + bo) = lv;
                }
            }
            __syncthreads();                                  // E: ztL (+ptZ) ready
        }
        // ---- cooperative coalesced zs store (from pt z-transpose) ----
        const long zrow = (long)step * BATCH + (long)blockIdx.x * 32;
        for (int ii = tid; ii < 1024; ii += 512) {
            const int sp = ii >> 5, lat0 = (ii & 31) * 4;
            f32x4v v;
            #pragma unroll
            for (int j = 0; j < 4; ++j)
                v[j] = pt[(lat0 + j) * 32 + (sp ^ ((lat0 + j) & 31))];
            *(f32x4v*)(zs + (zrow + sp) * 128 + lat0) = v;
        }
    }
}

// ---------------------------------------------------------------------------
// Decode: hs = leaky(zs@Wl+bl); xs = hs@Wo+bo.  fp16 MFMA (no split needed).
// grid = T*B/32 = 16384 blocks x 512 thr.
// ---------------------------------------------------------------------------
__global__ __launch_bounds__(512, 4) void dec_kernel(
    const float* __restrict__ zsin, const _Float16* __restrict__ wlt,
    const float* __restrict__ bl, const float* __restrict__ Wo,
    const float* __restrict__ bo, float* __restrict__ xs)
{
    __shared__ _Float16 zH[32 * 128];      // [row][lat] swizzled
    __shared__ float wo4[256][8];          // [hid][o]
    __shared__ float bl_s[256];
    __shared__ float scrX[8][32][8];       // [wave][row][o]
    __shared__ float bo_s[8];

    const int tid = threadIdx.x;
    const int w = tid >> 6, l = tid & 63, li = l & 31, lh = l >> 5;
    const long r0 = (long)blockIdx.x * 32;
    char* zB = (char*)zH;

    if (tid < 256) bl_s[tid] = bl[tid];
    for (int i = tid; i < 256 * 8; i += 512) wo4[i >> 3][i & 7] = Wo[i];
    if (tid < 8) bo_s[tid] = bo[tid];

    // stage 32 zs rows -> fp16 swizzled LDS (coalesced f32x4 loads)
    for (int ii = tid; ii < 1024; ii += 512) {
        const int row = ii >> 5, lat0 = (ii & 31) * 4;
        f32x4v v = *(const f32x4v*)(zsin + (r0 + row) * 128 + lat0);
        f16x4 hv;
        #pragma unroll
        for (int j = 0; j < 4; ++j) hv[j] = (_Float16)v[j];
        const int slot = lat0 >> 3;
        *(f16x4*)(zB + row * 256 + ((slot ^ (row & 15)) << 4) + (lat0 & 7) * 2) = hv;
    }

    f16x8 wl8[8];
    #pragma unroll
    for (int kt = 0; kt < 8; ++kt)
        wl8[kt] = *(const f16x8*)(wlt + (32 * w + li) * 128 + kt * 16 + lh * 8);
    __syncthreads();

    f32x16 acc = {};
    #pragma unroll
    for (int kt = 0; kt < 8; ++kt) {
        const int kc = kt * 2 + lh;
        f16x8 b = *(const f16x8*)(zB + li * 256 + ((kc ^ (li & 15)) << 4));
        acc = __builtin_amdgcn_mfma_f32_32x32x16_f16(wl8[kt], b, acc, 0, 0, 0);
    }

    float xo[8];
    #pragma unroll
    for (int o = 0; o < 8; ++o) xo[o] = 0.f;
    #pragma unroll
    for (int rg = 0; rg < 4; ++rg) {
        #pragma unroll
        for (int j = 0; j < 4; ++j) {
            const int hid = 32 * w + 8 * rg + 4 * lh + j;
            float a = acc[rg * 4 + j] + bl_s[hid];
            a = fmaxf(a, 0.1f * a);
            const float4 wa = *(const float4*)&wo4[hid][0];   // broadcast reads
            const float4 wb = *(const float4*)&wo4[hid][4];
            xo[0] = fmaf(a, wa.x, xo[0]); xo[1] = fmaf(a, wa.y, xo[1]);
            xo[2] = fmaf(a, wa.z, xo[2]); xo[3] = fmaf(a, wa.w, xo[3]);
            xo[4] = fmaf(a, wb.x, xo[4]); xo[5] = fmaf(a, wb.y, xo[5]);
            xo[6] = fmaf(a, wb.z, xo[6]); xo[7] = fmaf(a, wb.w, xo[7]);
        }
    }
    #pragma unroll
    for (int o = 0; o < 8; ++o) xo[o] += __shfl_xor(xo[o], 32);
    if (l < 32) {
        *(float4*)&scrX[w][li][0] = make_float4(xo[0], xo[1], xo[2], xo[3]);
        *(float4*)&scrX[w][li][4] = make_float4(xo[4], xo[5], xo[6], xo[7]);
    }
    __syncthreads();
    if (tid < 256) {
        const int row = tid >> 3, o = tid & 7;
        float s = bo_s[o];
        #pragma unroll
        for (int ww = 0; ww < 8; ++ww) s += scrX[ww][row][o];
        xs[(r0 + row) * 8 + o] = s;
    }
}

extern "C" void kernel_launch(void* const* d_in, const int* in_sizes, int n_in,
                              void* d_out, int out_size, void* d_ws, size_t ws_size,
                              hipStream_t stream) {
    const float* z0  = (const float*)d_in[0];
    const float* ts  = (const float*)d_in[1];
    const float* W1  = (const float*)d_in[2];
    const float* b1  = (const float*)d_in[3];
    const float* g1  = (const float*)d_in[4];
    const float* be1 = (const float*)d_in[5];
    const float* W2  = (const float*)d_in[6];
    const float* b2  = (const float*)d_in[7];
    const float* g2  = (const float*)d_in[8];
    const float* be2 = (const float*)d_in[9];
    const float* Wl  = (const float*)d_in[10];
    const float* bl  = (const float*)d_in[11];
    const float* Wo  = (const float*)d_in[12];
    const float* bo  = (const float*)d_in[13];

    float* xs = (float*)d_out;                                  // [T,B,8]
    float* zs = (float*)d_out + (size_t)TSTEPS * BATCH * NOUT;  // [T,B,128]

    // workspace layout (all f16 arrays first; 8B-aligned tail)
    _Float16* w1h = (_Float16*)d_ws;                  // [256][128]
    _Float16* w1l = w1h + 32768;
    _Float16* w2h = w1l + 32768;                      // [128][256]
    _Float16* w2l = w2h + 32768;
    _Float16* wlt = w2l + 32768;                      // [256][128]
    float2* pA  = (float2*)(wlt + 32768);             // [256] {b1, w1_time}
    float2* pB  = pA + 256;                           // [256] {g1, be1}
    float2* pD  = pB + 256;                           // [128] {g2, be2}
    float*  b2f = (float*)(pD + 128);                 // [128]

    prep_kernel<<<dim3(128), dim3(256), 0, stream>>>(
        W1, b1, g1, be1, W2, b2, g2, be2, Wl,
        w1h, w1l, w2h, w2l, wlt, pA, pB, pD, b2f);
    ode_kernel<<<dim3(BATCH / 32), dim3(512), 0, stream>>>(
        z0, ts, w1h, w1l, w2h, w2l, pA, pB, pD, b2f, zs);
    dec_kernel<<<dim3(TSTEPS * BATCH / 32), dim3(512), 0, stream>>>(
        zs, wlt, bl, Wo, bo, xs);
}